// Round 8
// baseline (556.275 us; speedup 1.0000x reference)
//
#include <hip/hip_runtime.h>
#include <math.h>

#define D_TOT 480

typedef short bf16x8 __attribute__((ext_vector_type(8)));
typedef float f32x4 __attribute__((ext_vector_type(4)));
typedef float floatx4 __attribute__((ext_vector_type(4)));

#define MFMA16(a, b, c) __builtin_amdgcn_mfma_f32_16x16x32_bf16((a), (b), (c), 0, 0, 0)

// dynamic LDS layout (bytes):
//   [0, 86016)          B-pack (bf16 fragments)
//   [86016, 151552)     x-tiles, 16 KB per wave (4 waves)
//   [151552, 159744)    uni-flush buffer (4 x 512 floats)
#define LDS_TOTAL 159744
#define LDS_X_OFF 86016
#define LDS_BUF_OFF 151552

static __device__ __forceinline__ unsigned short f2bf(float x) {
  unsigned u = __float_as_uint(x);
  u += 0x7FFFu + ((u >> 16) & 1u);   // RNE (inputs finite)
  return (unsigned short)(u >> 16);
}
static __device__ __forceinline__ float bf2f(unsigned short v) {
  return __uint_as_float(((unsigned)v) << 16);
}

// ---------------------------------------------------------------------------
// K0: Mtmp_b = (Wq_b . Wd_b . Wk_b^T) * scale_b (fp32), scale folds all norms.
// ---------------------------------------------------------------------------
__global__ __launch_bounds__(256) void precompute_M(
    const float* __restrict__ Wq0, const float* __restrict__ Wq1, const float* __restrict__ Wq2,
    const float* __restrict__ Wk0, const float* __restrict__ Wk1, const float* __restrict__ Wk2,
    const float* __restrict__ Wd0, const float* __restrict__ Wd1, const float* __restrict__ Wd2,
    float* __restrict__ ws) {
  __shared__ float T[16 * 128];
  int b = blockIdx.x;
  const float *Wq, *Wk, *Wd;
  float* M;
  int m, deg, strip;
  if (b < 8)       { Wq = Wq0; Wk = Wk0; Wd = Wd0; M = ws;         m = 128; deg = 1; strip = b; }
  else if (b < 12) { Wq = Wq1; Wk = Wk1; Wd = Wd1; M = ws + 16384; m = 64;  deg = 3; strip = b - 8; }
  else if (b < 14) { Wq = Wq2; Wk = Wk2; Wd = Wd2; M = ws + 20480; m = 32;  deg = 5; strip = b - 12; }
  else return;
  int r0 = strip * 16;
  if (r0 >= m) return;
  float scale = 1.0f / ((float)m * (float)m * sqrtf(1440.0f * (float)deg));
  for (int idx = threadIdx.x; idx < 16 * m; idx += 256) {
    int r = idx / m, c = idx % m;
    float s = 0.f;
    for (int a = 0; a < m; ++a) s += Wq[(r0 + r) * m + a] * Wd[a * m + c];
    T[r * m + c] = s;
  }
  __syncthreads();
  for (int idx = threadIdx.x; idx < 16 * m; idx += 256) {
    int r = idx / m, j = idx % m;
    float s = 0.f;
    for (int c = 0; c < m; ++c) s += T[r * m + c] * Wk[j * m + c];
    M[(r0 + r) * m + j] = s * scale;
  }
}

// ---------------------------------------------------------------------------
// K0b: pack B = [M_b | Wv_b/sqrt(m)] (bf16) in per-MFMA-fragment layout.
// Fragment = 1 KB: elem (l,j) = B[k = kt*32+(l>>4)*8+j][c = ct*16+(l&15)].
// ---------------------------------------------------------------------------
__global__ __launch_bounds__(256) void pack_B(
    const float* __restrict__ Mtmp,
    const float* __restrict__ Wv0, const float* __restrict__ Wv1, const float* __restrict__ Wv2,
    unsigned short* __restrict__ Bp) {
  int idx = blockIdx.x * 256 + threadIdx.x;
  if (idx >= 43008) return;
  float val;
  if (idx < 32768) {
    int fragi = idx >> 9, rem = idx & 511;
    int l = rem >> 3, j = rem & 7;
    int ct = fragi >> 2, kt = fragi & 3;
    int k = kt * 32 + (l >> 4) * 8 + j;
    int c = ct * 16 + (l & 15);
    val = (c < 128) ? Mtmp[k * 128 + c] : Wv0[k * 128 + (c - 128)] * 0.08838834764831845f;
  } else if (idx < 40960) {
    int i1 = idx - 32768;
    int fragi = i1 >> 9, rem = i1 & 511;
    int l = rem >> 3, j = rem & 7;
    int ct = fragi >> 1, kt = fragi & 1;
    int k = kt * 32 + (l >> 4) * 8 + j;
    int c = ct * 16 + (l & 15);
    val = (c < 64) ? Mtmp[16384 + k * 64 + c] : Wv1[k * 64 + (c - 64)] * 0.125f;
  } else {
    int i2 = idx - 40960;
    int ct = i2 >> 9, rem = i2 & 511;
    int l = rem >> 3, j = rem & 7;
    int k = (l >> 4) * 8 + j;
    int c = ct * 16 + (l & 15);
    val = (c < 32) ? Mtmp[20480 + k * 32 + c] : Wv2[k * 32 + (c - 32)] * 0.17677669529663687f;
  }
  Bp[idx] = f2bf(val);
}

// ---------------------------------------------------------------------------
// Fused MFMA kernel. B-pack staged in LDS once per block (shared by 4 waves).
// Grid-stride over 64-node windows (dispatch-order locality); one 16-node
// tile per wave per window. x-tile LDS (natural layout + XOR swizzle) used
// ONLY for the logit dot; A-fragments loaded directly from global windows.
// ---------------------------------------------------------------------------
__global__ __launch_bounds__(256) void fused_mfma_kernel(
    const float* __restrict__ f, const unsigned short* __restrict__ Bpack,
    const int* __restrict__ batch,
    float* __restrict__ outnum, float* __restrict__ norm, int N, int nwin) {
  extern __shared__ __align__(16) char smem[];
  int t = threadIdx.x;
  int w = t >> 6, lane = t & 63;
  int q = lane >> 4, lm = lane & 15;

  char* lB = smem;
  char* xsb = smem + LDS_X_OFF + w * 16384;
  float* buf = (float*)(smem + LDS_BUF_OFF);

  // ---- stage B-pack into LDS (once per block) ----
  {
    const uint4* src = reinterpret_cast<const uint4*>(Bpack);
    uint4* dst = reinterpret_cast<uint4*>(lB);
    for (int i = t; i < 5376; i += 256) dst[i] = src[i];
  }
  __syncthreads();

  const bf16x8* B0f = (const bf16x8*)lB;
  const bf16x8* B1f = (const bf16x8*)(lB + 65536);
  const bf16x8* B2f = (const bf16x8*)(lB + 81920);

  auto wavered = [&](float s) -> float {
    s += __shfl_xor(s, 16);
    s += __shfl_xor(s, 32);
    return s;
  };

  for (int win = blockIdx.x; win < nwin; win += gridDim.x) {
    int blockbase = win * 64;
    int nt = blockbase + w * 16;
    bool uni = (blockbase + 63 < N) && (batch[blockbase] == batch[blockbase + 63]);

    if (nt < N) {
      int valid = min(16, N - nt);

      // ---- stage x-tile: 16 nodes x 480 fp32 -> bf16 rows (swizzled), NT ----
      {
        int ns = lane >> 2, e0 = lane & 3;
        const floatx4* frow4 = reinterpret_cast<const floatx4*>(f + (size_t)(nt + ns) * 480);
        char* wrow = xsb + ns * 1024;
        unsigned swzw = (unsigned)((ns & 7) << 4);
        bool okn = ns < valid;
#pragma unroll
        for (int i = 0; i < 30; ++i) {
          int e4 = e0 + i * 4;
          floatx4 xv = {0.f, 0.f, 0.f, 0.f};
          if (okn) xv = __builtin_nontemporal_load(frow4 + e4);
          unsigned p0 = (unsigned)f2bf(xv[0]) | ((unsigned)f2bf(xv[1]) << 16);
          unsigned p1 = (unsigned)f2bf(xv[2]) | ((unsigned)f2bf(xv[3]) << 16);
          *reinterpret_cast<uint2*>(wrow + (((unsigned)(e4 * 8)) ^ swzw)) = make_uint2(p0, p1);
        }
      }

      // ---- A-frags direct from global (row = lm, k-chunk = q) ----
      long rr = nt + (lm < valid ? lm : valid - 1);
      const float4* fr4 = reinterpret_cast<const float4*>(f + rr * 480);
      bf16x8 a0[4], a1[3][2], a2[5];
#pragma unroll
      for (int ks = 0; ks < 4; ++ks) {
        float4 A = fr4[ks * 8 + 2 * q];
        float4 B = fr4[ks * 8 + 2 * q + 1];
        bf16x8 v;
        v[0] = (short)f2bf(A.x); v[1] = (short)f2bf(A.y);
        v[2] = (short)f2bf(A.z); v[3] = (short)f2bf(A.w);
        v[4] = (short)f2bf(B.x); v[5] = (short)f2bf(B.y);
        v[6] = (short)f2bf(B.z); v[7] = (short)f2bf(B.w);
        a0[ks] = v;
      }
#pragma unroll
      for (int h = 0; h < 2; ++h) {
        unsigned short b[24];
#pragma unroll
        for (int i = 0; i < 6; ++i) {
          float4 x4 = fr4[32 + 24 * h + 6 * q + i];
          b[i * 4 + 0] = f2bf(x4.x); b[i * 4 + 1] = f2bf(x4.y);
          b[i * 4 + 2] = f2bf(x4.z); b[i * 4 + 3] = f2bf(x4.w);
        }
#pragma unroll
        for (int d = 0; d < 3; ++d) {
          bf16x8 v;
#pragma unroll
          for (int j = 0; j < 8; ++j) v[j] = (short)b[3 * j + d];
          a1[d][h] = v;
        }
      }
      {
        unsigned short b[40];
#pragma unroll
        for (int i = 0; i < 10; ++i) {
          float4 x4 = fr4[80 + 10 * q + i];
          b[i * 4 + 0] = f2bf(x4.x); b[i * 4 + 1] = f2bf(x4.y);
          b[i * 4 + 2] = f2bf(x4.z); b[i * 4 + 3] = f2bf(x4.w);
        }
#pragma unroll
        for (int d = 0; d < 5; ++d) {
          bf16x8 v;
#pragma unroll
          for (int j = 0; j < 8; ++j) v[j] = (short)b[5 * j + d];
          a2[d] = v;
        }
      }

      // x read in C-frag order for logit dot: node = q*4+r, natural col c
      auto ldx = [&](int node, int c) -> float {
        unsigned off = ((unsigned)(2 * c)) ^ ((unsigned)((node & 7) << 4));
        return bf2f(*reinterpret_cast<const unsigned short*>(xsb + node * 1024 + off));
      };

      // ---- u-phase: logits ----
      float pl0 = 0.f, pl1 = 0.f, pl2 = 0.f, pl3 = 0.f;
#pragma unroll
      for (int ct = 0; ct < 8; ++ct) {
        f32x4 u = {0.f, 0.f, 0.f, 0.f};
        u = MFMA16(a0[0], B0f[(ct * 4 + 0) * 64 + lane], u);
        u = MFMA16(a0[1], B0f[(ct * 4 + 1) * 64 + lane], u);
        u = MFMA16(a0[2], B0f[(ct * 4 + 2) * 64 + lane], u);
        u = MFMA16(a0[3], B0f[(ct * 4 + 3) * 64 + lane], u);
        int c = ct * 16 + lm;
        pl0 += u[0] * ldx(q * 4 + 0, c);
        pl1 += u[1] * ldx(q * 4 + 1, c);
        pl2 += u[2] * ldx(q * 4 + 2, c);
        pl3 += u[3] * ldx(q * 4 + 3, c);
      }
#pragma unroll
      for (int d = 0; d < 3; ++d)
#pragma unroll
        for (int ct = 0; ct < 4; ++ct) {
          f32x4 u = {0.f, 0.f, 0.f, 0.f};
          u = MFMA16(a1[d][0], B1f[(ct * 2 + 0) * 64 + lane], u);
          u = MFMA16(a1[d][1], B1f[(ct * 2 + 1) * 64 + lane], u);
          int c = 128 + 3 * (ct * 16 + lm) + d;
          pl0 += u[0] * ldx(q * 4 + 0, c);
          pl1 += u[1] * ldx(q * 4 + 1, c);
          pl2 += u[2] * ldx(q * 4 + 2, c);
          pl3 += u[3] * ldx(q * 4 + 3, c);
        }
#pragma unroll
      for (int d = 0; d < 5; ++d)
#pragma unroll
        for (int ct = 0; ct < 2; ++ct) {
          f32x4 u = {0.f, 0.f, 0.f, 0.f};
          u = MFMA16(a2[d], B2f[ct * 64 + lane], u);
          int c = 320 + 5 * (ct * 16 + lm) + d;
          pl0 += u[0] * ldx(q * 4 + 0, c);
          pl1 += u[1] * ldx(q * 4 + 1, c);
          pl2 += u[2] * ldx(q * 4 + 2, c);
          pl3 += u[3] * ldx(q * 4 + 3, c);
        }
#pragma unroll
      for (int off = 1; off < 16; off <<= 1) {
        pl0 += __shfl_xor(pl0, off);
        pl1 += __shfl_xor(pl1, off);
        pl2 += __shfl_xor(pl2, off);
        pl3 += __shfl_xor(pl3, off);
      }
      float w0 = (q * 4 + 0 < valid) ? __expf(pl0) : 0.f;
      float w1 = (q * 4 + 1 < valid) ? __expf(pl1) : 0.f;
      float w2 = (q * 4 + 2 < valid) ? __expf(pl2) : 0.f;
      float w3 = (q * 4 + 3 < valid) ? __expf(pl3) : 0.f;

      // ---- v accumulators ----
      float r0[8], r1[3][4], r2[5][2], naccw = 0.f;
#pragma unroll
      for (int i = 0; i < 8; ++i) r0[i] = 0.f;
#pragma unroll
      for (int d = 0; d < 3; ++d)
#pragma unroll
        for (int i = 0; i < 4; ++i) r1[d][i] = 0.f;
#pragma unroll
      for (int d = 0; d < 5; ++d)
#pragma unroll
        for (int i = 0; i < 2; ++i) r2[d][i] = 0.f;

      auto vpass = [&](float vw0, float vw1, float vw2, float vw3) {
        if (lm == 0) naccw += vw0 + vw1 + vw2 + vw3;
#pragma unroll
        for (int ct = 0; ct < 8; ++ct) {
          f32x4 v = {0.f, 0.f, 0.f, 0.f};
          v = MFMA16(a0[0], B0f[((ct + 8) * 4 + 0) * 64 + lane], v);
          v = MFMA16(a0[1], B0f[((ct + 8) * 4 + 1) * 64 + lane], v);
          v = MFMA16(a0[2], B0f[((ct + 8) * 4 + 2) * 64 + lane], v);
          v = MFMA16(a0[3], B0f[((ct + 8) * 4 + 3) * 64 + lane], v);
          r0[ct] += vw0 * v[0] + vw1 * v[1] + vw2 * v[2] + vw3 * v[3];
        }
#pragma unroll
        for (int d = 0; d < 3; ++d)
#pragma unroll
          for (int ct = 0; ct < 4; ++ct) {
            f32x4 v = {0.f, 0.f, 0.f, 0.f};
            v = MFMA16(a1[d][0], B1f[((ct + 4) * 2 + 0) * 64 + lane], v);
            v = MFMA16(a1[d][1], B1f[((ct + 4) * 2 + 1) * 64 + lane], v);
            r1[d][ct] += vw0 * v[0] + vw1 * v[1] + vw2 * v[2] + vw3 * v[3];
          }
#pragma unroll
        for (int d = 0; d < 5; ++d)
#pragma unroll
          for (int ct = 0; ct < 2; ++ct) {
            f32x4 v = {0.f, 0.f, 0.f, 0.f};
            v = MFMA16(a2[d], B2f[(ct + 2) * 64 + lane], v);
            r2[d][ct] += vw0 * v[0] + vw1 * v[1] + vw2 * v[2] + vw3 * v[3];
          }
      };

      if (uni) {
        // ---- fast path: whole 64-node window is one graph ----
        vpass(w0, w1, w2, w3);
        __syncthreads();
#pragma unroll
        for (int ct = 0; ct < 8; ++ct) {
          float sv = wavered(r0[ct]);
          if (lane < 16) buf[w * 512 + ct * 16 + lane] = sv;
        }
#pragma unroll
        for (int d = 0; d < 3; ++d)
#pragma unroll
          for (int ct = 0; ct < 4; ++ct) {
            float sv = wavered(r1[d][ct]);
            if (lane < 16) buf[w * 512 + 128 + 3 * (ct * 16 + lane) + d] = sv;
          }
#pragma unroll
        for (int d = 0; d < 5; ++d)
#pragma unroll
          for (int ct = 0; ct < 2; ++ct) {
            float sv = wavered(r2[d][ct]);
            if (lane < 16) buf[w * 512 + 320 + 5 * (ct * 16 + lane) + d] = sv;
          }
        {
          float sw = wavered(naccw);
          if (lane == 0) buf[w * 512 + 480] = sw;
        }
        __syncthreads();
        int gg = batch[blockbase];
        float* og = outnum + (size_t)gg * 480;
        for (int c = t; c < 480; c += 256) {
          float s = buf[c] + buf[512 + c] + buf[1024 + c] + buf[1536 + c];
          atomicAdd(og + c, s);
        }
        if (t == 0) {
          float s = buf[480] + buf[992] + buf[1504] + buf[2016];
          atomicAdd(norm + gg, s);
        }
      } else {
        // ---- general path: per-wave segmented flush ----
        auto flushf = [&](int g) {
          float* og = outnum + (size_t)g * 480;
#pragma unroll
          for (int ct = 0; ct < 8; ++ct) {
            float s = wavered(r0[ct]);
            if (lane < 16) atomicAdd(og + ct * 16 + lane, s);
            r0[ct] = 0.f;
          }
#pragma unroll
          for (int d = 0; d < 3; ++d)
#pragma unroll
            for (int ct = 0; ct < 4; ++ct) {
              float s = wavered(r1[d][ct]);
              if (lane < 16) atomicAdd(og + 128 + 3 * (ct * 16 + lane) + d, s);
              r1[d][ct] = 0.f;
            }
#pragma unroll
          for (int d = 0; d < 5; ++d)
#pragma unroll
            for (int ct = 0; ct < 2; ++ct) {
              float s = wavered(r2[d][ct]);
              if (lane < 16) atomicAdd(og + 320 + 5 * (ct * 16 + lane) + d, s);
              r2[d][ct] = 0.f;
            }
          float sw = wavered(naccw);
          if (lane == 0) atomicAdd(norm + g, sw);
          naccw = 0.f;
        };

        int gl = batch[nt + (lm < valid ? lm : valid - 1)];
        int gp = __shfl(gl, (lane == 0) ? 0 : lane - 1);
        unsigned long long bm = __ballot(lm > 0 && lm < valid && gl != gp);
        unsigned segm = (unsigned)bm & 0xFFFEu;

        int cur_g = -1;
        int a = 0;
        while (a < valid) {
          unsigned hi = segm & ~((1u << (a + 1)) - 1u);
          int b = hi ? (int)__builtin_ctz(hi) : valid;
          int gs = __shfl(gl, a);
          if (cur_g >= 0) flushf(cur_g);
          cur_g = gs;
          int nq = q * 4;
          float m0 = (nq + 0 >= a && nq + 0 < b) ? w0 : 0.f;
          float m1 = (nq + 1 >= a && nq + 1 < b) ? w1 : 0.f;
          float m2 = (nq + 2 >= a && nq + 2 < b) ? w2 : 0.f;
          float m3 = (nq + 3 >= a && nq + 3 < b) ? w3 : 0.f;
          vpass(m0, m1, m2, m3);
          a = b;
        }
        if (cur_g >= 0) flushf(cur_g);
      }
    }
  }
}

// ---------------------------------------------------------------------------
// finalize: out = num / max(norm, 1e-8)
// ---------------------------------------------------------------------------
__global__ __launch_bounds__(256) void finalize_kernel(
    float* __restrict__ out, const float* __restrict__ norm, int total) {
  int idx = blockIdx.x * blockDim.x + threadIdx.x;
  if (idx < total) {
    int g = idx / 480;
    out[idx] = out[idx] / fmaxf(norm[g], 1e-8f);
  }
}

extern "C" void kernel_launch(void* const* d_in, const int* in_sizes, int n_in,
                              void* d_out, int out_size, void* d_ws, size_t ws_size,
                              hipStream_t stream) {
  const float* f   = (const float*)d_in[0];
  const float* Wv0 = (const float*)d_in[7];
  const float* Wv1 = (const float*)d_in[8];
  const float* Wv2 = (const float*)d_in[9];
  const int* batch = (const int*)d_in[13];

  int N = in_sizes[0] / D_TOT;
  int G = out_size / D_TOT;

  // ws bytes: [0,86016) Mtmp fp32; [86016,172032) Bpack bf16; [172032,..) norm
  float* Mtmp = (float*)d_ws;
  unsigned short* Bpack = (unsigned short*)((char*)d_ws + 86016);
  float* norm = (float*)((char*)d_ws + 172032);
  float* out  = (float*)d_out;

  // opt-in to >64 KB dynamic LDS (idempotent, host-side; graph-capture safe)
  hipFuncSetAttribute((const void*)fused_mfma_kernel,
                      hipFuncAttributeMaxDynamicSharedMemorySize, LDS_TOTAL);

  hipMemsetAsync(d_out, 0, (size_t)out_size * sizeof(float), stream);
  hipMemsetAsync(norm, 0, (size_t)G * sizeof(float), stream);

  precompute_M<<<14, 256, 0, stream>>>(
      (const float*)d_in[1], (const float*)d_in[2], (const float*)d_in[3],
      (const float*)d_in[4], (const float*)d_in[5], (const float*)d_in[6],
      (const float*)d_in[10], (const float*)d_in[11], (const float*)d_in[12], Mtmp);

  pack_B<<<(43008 + 255) / 256, 256, 0, stream>>>(Mtmp, Wv0, Wv1, Wv2, Bpack);

  int nwin = (N + 63) / 64;
  int nblocks = 512;
  if (nblocks > nwin) nblocks = nwin;
  fused_mfma_kernel<<<nblocks, 256, LDS_TOTAL, stream>>>(
      f, Bpack, batch, out, norm, N, nwin);

  finalize_kernel<<<(G * D_TOT + 255) / 256, 256, 0, stream>>>(out, norm, G * D_TOT);
}